// Round 2
// baseline (390.466 us; speedup 1.0000x reference)
//
#include <hip/hip_runtime.h>

// CondLaneHead dynamic mask head, fp32, spill-free.
// N=4 imgs x 8 inst -> 32 instances; C=64, CIN=66, H=160, W=256, L=40960.
//
// Params per instance (8513 floats):
//   [0:4224)    w0 (64 x 66) row-major o*66+c
//   [4224:8320) w1 (64 x 64) row-major o*64+c   <- read as rows, no transpose
//   [8320:8384) w2 (1 x 64)
//   [8384:8448) b0
//   [8448:8512) b1
//   [8512]      b2 (mask bias shift -2.19 applied in main)
//
// Workspace: per-instance w0T (66 x 64, layout c*64+o), stride 4224 floats.
// Key correctness-of-performance rule: every index into the per-thread h[]
// array must be a compile-time constant, or LLVM demotes it to scratch
// (round 1: 629 MB scratch writes, 2.3x slowdown). Layers 2+3 are fused so
// h2 never exists; the o loop is runtime (unroll 4 for 4 independent FMA
// chains) but only indexes uniform weight rows, never h[].

#define NP   8513
#define W0T  4224
#define HW   40960
#define CC   64

__global__ void condlane_prep(const float* __restrict__ params,
                              float* __restrict__ wt) {
  const int inst = blockIdx.x;
  const float* __restrict__ p = params + inst * NP;
  float* __restrict__ o = wt + inst * W0T;
  // w0 transpose: dest[c*64+r] = src[r*66+c]
  for (int idx = threadIdx.x; idx < 4224; idx += 256) {
    const int c = idx >> 6, r = idx & 63;
    o[idx] = p[r * 66 + c];
  }
}

__global__ __launch_bounds__(256, 3) void condlane_main(
    const float* __restrict__ x, const float* __restrict__ params,
    const float* __restrict__ wt, float* __restrict__ out) {
  const int inst = blockIdx.y;                   // 0..31
  const int p = blockIdx.x * 256 + threadIdx.x;  // 0..40959
  const float* __restrict__ w0t = wt + inst * W0T;      // uniform -> s_load
  const float* __restrict__ pp  = params + inst * NP;   // uniform -> s_load
  const float* __restrict__ xp  = x + (inst >> 3) * (CC * HW) + p;
  const float fx = (float)(p & 255);   // loc_x (W=256)
  const float fy = (float)(p >> 8);    // loc_y

  // ---- layer 1: h[o] = b0[o] + w0[o,0]*fx + w0[o,1]*fy + sum_c w0[o,c+2]*x[c]
  float h[64];
#pragma unroll
  for (int o = 0; o < 64; o++)
    h[o] = fmaf(w0t[o], fx, fmaf(w0t[64 + o], fy, pp[8384 + o]));

#pragma unroll 4
  for (int c = 0; c < 64; c++) {
    const float f = xp[c * HW];                         // coalesced across lanes
    const float* __restrict__ wr = w0t + (c + 2) * 64;  // uniform row
#pragma unroll
    for (int o = 0; o < 64; o++) h[o] = fmaf(wr[o], f, h[o]);  // const idx
  }

  // relu in place (const idx)
#pragma unroll
  for (int o = 0; o < 64; o++) h[o] = fmaxf(h[o], 0.0f);

  // ---- layers 2+3 fused: acc = b2-2.19 + sum_o w2[o]*relu(b1[o] + w1[o,:].h)
  float acc = pp[8512] - 2.19f;
#pragma unroll 4
  for (int o = 0; o < 64; o++) {
    const float* __restrict__ wr = pp + 4224 + o * 64;  // w1 row o, uniform
    float s = pp[8448 + o];                             // b1[o]
#pragma unroll
    for (int c = 0; c < 64; c++) s = fmaf(wr[c], h[c], s);  // const idx into h
    acc = fmaf(pp[8320 + o], fmaxf(s, 0.0f), acc);
  }

  out[inst * HW + p] = acc;
}

extern "C" void kernel_launch(void* const* d_in, const int* in_sizes, int n_in,
                              void* d_out, int out_size, void* d_ws, size_t ws_size,
                              hipStream_t stream) {
  const float* x      = (const float*)d_in[0];  // [4,64,160,256] fp32
  const float* params = (const float*)d_in[1];  // [32,8513] fp32
  // d_in[2] = num_ins (static, all 8) -- inst>>3 mapping hardcoded
  float* wt  = (float*)d_ws;                    // 32*4224*4 = 540,672 B
  float* out = (float*)d_out;

  condlane_prep<<<32, 256, 0, stream>>>(params, wt);
  condlane_main<<<dim3(160, 32), 256, 0, stream>>>(x, params, wt, out);
}

// Round 3
// 147.049 us; speedup vs baseline: 2.6553x; 2.6553x over previous
//
#include <hip/hip_runtime.h>

// CondLaneHead via bf16 MFMA (16x16x32), all 3 layers fused.
// 32 instances, C=64, H=160, W=256, L=40960 px.
//
// Layer1 as GEMM: D1[o][p] = sum_k A[o][k] * B[k][p], K=96:
//   k 0..63 : x channels (bf16, RNE)
//   k 64    : ones row      -> weight b0[o]
//   k 65,66 : fx row twice  -> weights wx_hi, wx_lo (hi/lo split: wx*255 needs it)
//   k 67,68 : fy row twice  -> weights wy_hi, wy_lo
//   k 69..95: zero pad
// Layer2: K=64, C-operand = b1 (free bias). Layer3: VALU dot + shfl butterfly.
//
// Frag layouts (m89/m120-verified): A[m=lane&15][k=(lane>>4)*8+j],
// B[k=(lane>>4)*8+j][n=lane&15], D[row=(lane>>4)*4+r][col=lane&15].
//
// prep bakes frag-ordered bf16 weights into ws so main's weight loads are
// coalesced dwordx4 from L2 (params fully L2-resident).

#define NP 8513
#define HW 40960
#define INST_STRIDE 28672
// per-inst ws: [0,12288) W0 frags [mt(4)][kst(3)][lane(64)] x 16B
//              [12288,20480) W1 frags [mt(4)][kst(2)][lane] x 16B
//              [20480,24576) b1 C-frags [mt(4)][lane] float4
//              [24576,28672) w2 frags   [mt(4)][lane] float4

typedef __attribute__((ext_vector_type(8))) short bf16x8;
typedef __attribute__((ext_vector_type(4))) float f32x4;

__device__ __host__ inline unsigned short f2bf(float f) {
  union { float f; unsigned u; } v; v.f = f;
  unsigned r = v.u + 0x7fffu + ((v.u >> 16) & 1u);   // RNE
  return (unsigned short)(r >> 16);
}
__device__ inline float bf2f(unsigned short b) {
  union { unsigned u; float f; } v; v.u = ((unsigned)b) << 16;
  return v.f;
}

__global__ void condlane_prep(const float* __restrict__ params,
                              char* __restrict__ ws) {
  const int inst = blockIdx.x;
  const float* __restrict__ p = params + inst * NP;
  char* base = ws + inst * INST_STRIDE;
  unsigned short* w0o = (unsigned short*)base;
  unsigned short* w1o = (unsigned short*)(base + 12288);
  float* b1o = (float*)(base + 20480);
  float* w2o = (float*)(base + 24576);

  // W0 frags: 12 frags x 64 lanes x 8 elems
  for (int e = threadIdx.x; e < 12 * 512; e += 256) {
    const int frag = e >> 9, rem = e & 511, lane = rem >> 3, j = rem & 7;
    const int mt = frag / 3, kst = frag % 3;
    const int m = mt * 16 + (lane & 15);
    const int k = kst * 32 + ((lane >> 4) << 3) + j;
    unsigned short bv;
    if (k < 64) bv = f2bf(p[m * 66 + 2 + k]);
    else if (k == 64) bv = f2bf(p[8384 + m]);                       // b0
    else if (k == 65) bv = f2bf(p[m * 66 + 0]);                     // wx hi
    else if (k == 66) { float wx = p[m * 66 + 0]; bv = f2bf(wx - bf2f(f2bf(wx))); }
    else if (k == 67) bv = f2bf(p[m * 66 + 1]);                     // wy hi
    else if (k == 68) { float wy = p[m * 66 + 1]; bv = f2bf(wy - bf2f(f2bf(wy))); }
    else bv = 0;
    w0o[frag * 512 + lane * 8 + j] = bv;
  }
  // W1 frags: 8 frags x 512
  for (int e = threadIdx.x; e < 8 * 512; e += 256) {
    const int frag = e >> 9, rem = e & 511, lane = rem >> 3, j = rem & 7;
    const int mt = frag >> 1, kst = frag & 1;
    const int m = mt * 16 + (lane & 15);
    const int k = kst * 32 + ((lane >> 4) << 3) + j;
    w1o[frag * 512 + lane * 8 + j] = f2bf(p[4224 + m * 64 + k]);
  }
  // b1 / w2 C-frags: 4 frags x 64 lanes x float4, row = (lane>>4)*4 + r
  for (int e = threadIdx.x; e < 4 * 256; e += 256) {
    const int mt = e >> 8, rem = e & 255, lane = rem >> 2, r = rem & 3;
    const int o = mt * 16 + ((lane >> 4) << 2) + r;
    b1o[mt * 256 + lane * 4 + r] = p[8448 + o];
    w2o[mt * 256 + lane * 4 + r] = p[8320 + o];
  }
}

__global__ __launch_bounds__(256, 2) void condlane_main(
    const float* __restrict__ x, const float* __restrict__ params,
    const char* __restrict__ ws, float* __restrict__ out) {
  __shared__ __align__(16) unsigned short xs[128 * 96];      // [px][96ch] 24KB
  __shared__ __align__(16) unsigned short hs[4 * 32 * 96];   // per-wave h 24KB
  const int img = blockIdx.y, chunk = blockIdx.x;
  const int px0 = chunk * 128;
  const int tid = threadIdx.x, lane = tid & 63, wave = tid >> 6;

  // ---- stage x chunk: 2 threads per pixel (ch halves) ----
  {
    const int px = tid & 127, half = tid >> 7;
    const int pg = px0 + px;
    const float* gx = x + img * 64 * HW + pg;
    unsigned short* row = xs + px * 96;
    const int c0 = half * 32;
#pragma unroll
    for (int cb = 0; cb < 4; cb++) {
      const int c = c0 + cb * 8;
      union { bf16x8 v; unsigned short s[8]; } u;
#pragma unroll
      for (int j = 0; j < 8; j++) u.s[j] = f2bf(gx[(c + j) * HW]);
      *(bf16x8*)(row + c) = u.v;
    }
    if (half == 1) {  // aug rows 64..95: [1, fx, fx, fy, fy, 0...]
      union { bf16x8 v; unsigned short s[8]; } u;
      u.s[0] = 0x3F80;                       // 1.0
      u.s[1] = f2bf((float)(pg & 255)); u.s[2] = u.s[1];   // fx exact in bf16
      u.s[3] = f2bf((float)(pg >> 8));  u.s[4] = u.s[3];   // fy exact
      u.s[5] = u.s[6] = u.s[7] = 0;
      *(bf16x8*)(row + 64) = u.v;
      bf16x8 z = {0, 0, 0, 0, 0, 0, 0, 0};
      *(bf16x8*)(row + 72) = z;
      *(bf16x8*)(row + 80) = z;
      *(bf16x8*)(row + 88) = z;
    }
  }
  __syncthreads();

  // ---- x B-frags to regs once; reused across all 8 instances ----
  bf16x8 bf[2][3];
  {
    const int r = lane & 15, kq = (lane >> 4) << 3;
#pragma unroll
    for (int nt = 0; nt < 2; nt++)
#pragma unroll
      for (int ks = 0; ks < 3; ks++)
        bf[nt][ks] = *(const bf16x8*)(xs + (wave * 32 + nt * 16 + r) * 96 + ks * 32 + kq);
  }
  unsigned short* hrow = hs + wave * 32 * 96;
  const f32x4 z4 = {0.f, 0.f, 0.f, 0.f};
  const int iid0 = img * 8;
  float* outp = out + px0 + wave * 32;

  for (int inst = 0; inst < 8; inst++) {
    const int iid = iid0 + inst;
    const char* wb = ws + iid * INST_STRIDE;
    const bf16x8* w0f = (const bf16x8*)wb;
    const bf16x8* w1f = (const bf16x8*)(wb + 12288);
    const f32x4* b1f = (const f32x4*)(wb + 20480);
    const f32x4* w2f = (const f32x4*)(wb + 24576);

    // ---- layer 1 ----
    f32x4 acc[4][2];
#pragma unroll
    for (int mt = 0; mt < 4; mt++) {
      bf16x8 a0 = w0f[(mt * 3 + 0) * 64 + lane];
      bf16x8 a1 = w0f[(mt * 3 + 1) * 64 + lane];
      bf16x8 a2 = w0f[(mt * 3 + 2) * 64 + lane];
#pragma unroll
      for (int nt = 0; nt < 2; nt++) {
        f32x4 c = __builtin_amdgcn_mfma_f32_16x16x32_bf16(a0, bf[nt][0], z4, 0, 0, 0);
        c = __builtin_amdgcn_mfma_f32_16x16x32_bf16(a1, bf[nt][1], c, 0, 0, 0);
        acc[mt][nt] = __builtin_amdgcn_mfma_f32_16x16x32_bf16(a2, bf[nt][2], c, 0, 0, 0);
      }
    }
    // ---- relu -> bf16 -> wave-local LDS (C-layout -> B-layout) ----
#pragma unroll
    for (int mt = 0; mt < 4; mt++)
#pragma unroll
      for (int nt = 0; nt < 2; nt++) {
        f32x4 v = acc[mt][nt];
        unsigned d0 = (unsigned)f2bf(fmaxf(v.x, 0.f)) | ((unsigned)f2bf(fmaxf(v.y, 0.f)) << 16);
        unsigned d1 = (unsigned)f2bf(fmaxf(v.z, 0.f)) | ((unsigned)f2bf(fmaxf(v.w, 0.f)) << 16);
        uint2 dd; dd.x = d0; dd.y = d1;
        *(uint2*)(hrow + (nt * 16 + (lane & 15)) * 96 + mt * 16 + ((lane >> 4) << 2)) = dd;
      }
    // same-wave ds ordering: compiler inserts lgkmcnt wait, no barrier needed
    bf16x8 hbf[2][2];
#pragma unroll
    for (int nt = 0; nt < 2; nt++)
#pragma unroll
      for (int ks = 0; ks < 2; ks++)
        hbf[nt][ks] = *(const bf16x8*)(hrow + (nt * 16 + (lane & 15)) * 96 + ks * 32 + ((lane >> 4) << 3));

    // ---- layer 2 (C-operand = b1, free bias) ----
    f32x4 acc2[4][2];
#pragma unroll
    for (int mt = 0; mt < 4; mt++) {
      bf16x8 a0 = w1f[(mt * 2 + 0) * 64 + lane];
      bf16x8 a1 = w1f[(mt * 2 + 1) * 64 + lane];
      f32x4 cb = b1f[mt * 64 + lane];
#pragma unroll
      for (int nt = 0; nt < 2; nt++) {
        f32x4 c = __builtin_amdgcn_mfma_f32_16x16x32_bf16(a0, hbf[nt][0], cb, 0, 0, 0);
        acc2[mt][nt] = __builtin_amdgcn_mfma_f32_16x16x32_bf16(a1, hbf[nt][1], c, 0, 0, 0);
      }
    }
    // ---- layer 3: relu dot w2, butterfly over the 4 row-groups ----
    float s0 = 0.f, s1 = 0.f;
#pragma unroll
    for (int mt = 0; mt < 4; mt++) {
      f32x4 w2v = w2f[mt * 64 + lane];
      f32x4 v0 = acc2[mt][0], v1 = acc2[mt][1];
      s0 += w2v.x * fmaxf(v0.x, 0.f); s1 += w2v.x * fmaxf(v1.x, 0.f);
      s0 += w2v.y * fmaxf(v0.y, 0.f); s1 += w2v.y * fmaxf(v1.y, 0.f);
      s0 += w2v.z * fmaxf(v0.z, 0.f); s1 += w2v.z * fmaxf(v1.z, 0.f);
      s0 += w2v.w * fmaxf(v0.w, 0.f); s1 += w2v.w * fmaxf(v1.w, 0.f);
    }
    s0 += __shfl_xor(s0, 16, 64); s0 += __shfl_xor(s0, 32, 64);
    s1 += __shfl_xor(s1, 16, 64); s1 += __shfl_xor(s1, 32, 64);
    const float b2 = params[iid * NP + 8512] - 2.19f;
    if (lane < 32) {
      const int nt = lane >> 4;
      outp[iid * HW + nt * 16 + (lane & 15)] = (nt ? s1 : s0) + b2;
    }
  }
}

extern "C" void kernel_launch(void* const* d_in, const int* in_sizes, int n_in,
                              void* d_out, int out_size, void* d_ws, size_t ws_size,
                              hipStream_t stream) {
  const float* x      = (const float*)d_in[0];  // [4,64,160,256] fp32
  const float* params = (const float*)d_in[1];  // [32,8513] fp32
  // d_in[2] = num_ins (static 8/img; inst mapping hardcoded)
  float* out = (float*)d_out;

  condlane_prep<<<32, 256, 0, stream>>>(params, (char*)d_ws);   // 917,504 B used
  condlane_main<<<dim3(320, 4), 256, 0, stream>>>(x, params, (const char*)d_ws, out);
}